// Round 1
// baseline (450.797 us; speedup 1.0000x reference)
//
#include <hip/hip_runtime.h>

// Per-row MLP: 5 -> 120 -> 84 -> 5, ReLU each, L2-normalize row of 5, mask by x!=0.
// One thread per row. Weights staged in LDS (W2 transposed for contiguous
// wave-uniform reads). f32 throughout to match the numpy reference.

__global__ __launch_bounds__(256) void nn_rows_kernel(
    const float* __restrict__ x,
    const float* __restrict__ W1, const float* __restrict__ b1,
    const float* __restrict__ W2, const float* __restrict__ b2,
    const float* __restrict__ W3, const float* __restrict__ b3,
    float* __restrict__ out, int nrows)
{
    __shared__ float s_w1[120 * 5];
    __shared__ float s_b1[120];
    __shared__ float s_w2t[120 * 84];   // s_w2t[h*84+g] = W2[g*120+h]
    __shared__ float s_b2[84];
    __shared__ float s_w3[5 * 84];
    __shared__ float s_b3[8];

    const int tid = threadIdx.x;
    for (int i = tid; i < 600; i += 256) s_w1[i] = W1[i];
    for (int i = tid; i < 120; i += 256) s_b1[i] = b1[i];
    for (int i = tid; i < 120 * 84; i += 256) {
        int g = i / 120;
        int h = i - g * 120;
        s_w2t[h * 84 + g] = W2[i];
    }
    for (int i = tid; i < 84; i += 256) s_b2[i] = b2[i];
    for (int i = tid; i < 420; i += 256) s_w3[i] = W3[i];
    if (tid < 5) s_b3[tid] = b3[tid];
    __syncthreads();

    const int row = blockIdx.x * 256 + tid;
    if (row >= nrows) return;

    const float* xr = x + (size_t)row * 5;
    float xv[5];
#pragma unroll
    for (int i = 0; i < 5; ++i) xv[i] = xr[i];

    // h2 accumulators, initialized with b2; stream h1 one value at a time.
    float acc[84];
#pragma unroll
    for (int g = 0; g < 84; ++g) acc[g] = s_b2[g];

    for (int h = 0; h < 120; ++h) {
        float a = s_b1[h];
        const float* w1r = &s_w1[h * 5];
        a = fmaf(w1r[0], xv[0], a);
        a = fmaf(w1r[1], xv[1], a);
        a = fmaf(w1r[2], xv[2], a);
        a = fmaf(w1r[3], xv[3], a);
        a = fmaf(w1r[4], xv[4], a);
        a = fmaxf(a, 0.0f);                 // relu(h1[h])
        const float* w2r = &s_w2t[h * 84];
#pragma unroll
        for (int g = 0; g < 84; ++g) acc[g] = fmaf(w2r[g], a, acc[g]);
    }

#pragma unroll
    for (int g = 0; g < 84; ++g) acc[g] = fmaxf(acc[g], 0.0f);  // relu(h2)

    float y[5];
#pragma unroll
    for (int o = 0; o < 5; ++o) {
        float a = s_b3[o];
        const float* w3r = &s_w3[o * 84];
#pragma unroll
        for (int g = 0; g < 84; ++g) a = fmaf(w3r[g], acc[g], a);
        y[o] = fmaxf(a, 0.0f);              // relu(out)
    }

    float ss = y[0] * y[0];
    ss = fmaf(y[1], y[1], ss);
    ss = fmaf(y[2], y[2], ss);
    ss = fmaf(y[3], y[3], ss);
    ss = fmaf(y[4], y[4], ss);
    const float nrm = sqrtf(ss);
    const float denom = fmaxf(nrm, 1e-12f);

    float* outr = out + (size_t)row * 5;
#pragma unroll
    for (int o = 0; o < 5; ++o) {
        outr[o] = (xv[o] != 0.0f) ? 0.0f : (y[o] / denom);
    }
}

extern "C" void kernel_launch(void* const* d_in, const int* in_sizes, int n_in,
                              void* d_out, int out_size, void* d_ws, size_t ws_size,
                              hipStream_t stream) {
    const float* x  = (const float*)d_in[0];
    const float* W1 = (const float*)d_in[1];
    const float* b1 = (const float*)d_in[2];
    const float* W2 = (const float*)d_in[3];
    const float* b2 = (const float*)d_in[4];
    const float* W3 = (const float*)d_in[5];
    const float* b3 = (const float*)d_in[6];
    float* out = (float*)d_out;

    const int nrows = in_sizes[0] / 5;       // B * 5 board-rows
    const int block = 256;
    const int grid = (nrows + block - 1) / block;
    nn_rows_kernel<<<grid, block, 0, stream>>>(x, W1, b1, W2, b2, W3, b3, out, nrows);
}